// Round 1
// baseline (44.850 us; speedup 1.0000x reference)
//
#include <hip/hip_runtime.h>

// Morton scatter re-expressed as gather:
//   out[plane][m] = in[plane][i][j],  j = compact-even-bits(m), i = compact-odd-bits(m)
// Each thread handles 8 consecutive m (m = 8T..8T+7):
//   k = m & 7:  j = 4*jq + {0,1,0,1,2,3,2,3}[k],  i = 2*ib + {0,0,1,1,0,0,1,1}[k]
// -> two float4 reads (rows 2ib, 2ib+1 at col 4jq), two float4 writes (contiguous).

__global__ __launch_bounds__(256) void morton_gather(const float* __restrict__ in,
                                                     float* __restrict__ out,
                                                     int nthreads) {
    const int stride = gridDim.x * blockDim.x;
    for (int t = blockIdx.x * blockDim.x + threadIdx.x; t < nthreads; t += stride) {
        const uint32_t T     = (uint32_t)t & 8191u;   // 13 bits: m bits 3..15
        const uint32_t plane = (uint32_t)t >> 13;     // (b,c) plane, 512 total

        // ib = i >> 1 : compact even bits of T (T bits 0,2,4,... -> i bits 1..7)
        uint32_t e = T & 0x5555u;
        e = (e | (e >> 1)) & 0x3333u;
        e = (e | (e >> 2)) & 0x0F0Fu;
        e = (e | (e >> 4)) & 0x00FFu;
        // jq = j >> 2 : compact even bits of (T>>1) (T bits 1,3,5,... -> j bits 2..7)
        uint32_t o = (T >> 1) & 0x5555u;
        o = (o | (o >> 1)) & 0x3333u;
        o = (o | (o >> 2)) & 0x0F0Fu;
        o = (o | (o >> 4)) & 0x00FFu;

        // input offset: plane*65536 + (2*ib)*256 + 4*jq
        const uint32_t base = (plane << 16) + (e << 9) + (o << 2);
        const float4* ip = reinterpret_cast<const float4*>(in + base);
        const float4 lo = ip[0];    // row 2*ib,   cols 4jq..4jq+3
        const float4 hi = ip[64];   // row 2*ib+1 (+256 floats = +64 float4)

        float4* op = reinterpret_cast<float4*>(out + ((size_t)t << 3));
        op[0] = make_float4(lo.x, lo.y, hi.x, hi.y);  // m offsets 0,1,2,3
        op[1] = make_float4(lo.z, lo.w, hi.z, hi.w);  // m offsets 4,5,6,7
    }
}

extern "C" void kernel_launch(void* const* d_in, const int* in_sizes, int n_in,
                              void* d_out, int out_size, void* d_ws, size_t ws_size,
                              hipStream_t stream) {
    const float* in = (const float*)d_in[0];
    float* out = (float*)d_out;
    const int nthreads = out_size / 8;          // 33,554,432 / 8 = 4,194,304
    const int block = 256;
    const int grid = 2048;                      // grid-stride, ~8 iters/thread
    morton_gather<<<grid, block, 0, stream>>>(in, out, nthreads);
}